// Round 1
// baseline (569.660 us; speedup 1.0000x reference)
//
#include <hip/hip_runtime.h>

// LightGCN propagation, CSR-by-destination formulation.
// N=100000 nodes, D=64 dims, E=1250000 edges (sizes read from in_sizes).
//
// Pipeline (all per call, no cached state):
//   1. memset deg/count
//   2. k_deg_count : atomic deg (f32) + in-degree count (int) by dst
//   3. k_dinv      : deg -> rsqrt(deg) in place
//   4. scan count  : chunk sums -> scan partials -> write row_start/cursor
//   5. k_fill      : w[e] = dinv[src]*attr*dinv[dst]; scatter (src,w) into CSR slots
//   6. k_out_init  : out = alpha*emb
//   7. k_layer x3  : per-node wave gather-accumulate; out += alpha*x_new
//
// Hot loop (k_layer) has no atomics: wave per node, lane d owns dim d.

#define SCAN_CHUNK 512

__global__ void k_deg_count(const int* __restrict__ ei, const float* __restrict__ ea,
                            float* __restrict__ deg, int* __restrict__ cnt, int E) {
    int stride = gridDim.x * blockDim.x;
    for (int e = blockIdx.x * blockDim.x + threadIdx.x; e < E; e += stride) {
        int d = ei[E + e];
        atomicAdd(&deg[d], ea[e]);
        atomicAdd(&cnt[d], 1);
    }
}

__global__ void k_dinv(float* __restrict__ deg, int N) {
    int i = blockIdx.x * blockDim.x + threadIdx.x;
    if (i < N) {
        float v = deg[i];
        deg[i] = (v > 0.0f) ? rsqrtf(v) : 0.0f;
    }
}

__global__ void k_chunk_sums(const int* __restrict__ cnt, int* __restrict__ partial, int N) {
    __shared__ int s[SCAN_CHUNK];
    int t = threadIdx.x;
    int i = blockIdx.x * SCAN_CHUNK + t;
    s[t] = (i < N) ? cnt[i] : 0;
    __syncthreads();
    for (int off = SCAN_CHUNK / 2; off > 0; off >>= 1) {
        if (t < off) s[t] += s[t + off];
        __syncthreads();
    }
    if (t == 0) partial[blockIdx.x] = s[0];
}

// single block, exclusive-scans up to 256 partials in place (nblk=196 for N=100000)
__global__ void k_scan_partials(int* __restrict__ partial, int nblk) {
    __shared__ int s[256];
    int t = threadIdx.x;
    int v = (t < nblk) ? partial[t] : 0;
    s[t] = v;
    __syncthreads();
    for (int off = 1; off < 256; off <<= 1) {
        int x = (t >= off) ? s[t - off] : 0;
        __syncthreads();
        s[t] += x;
        __syncthreads();
    }
    if (t < nblk) partial[t] = s[t] - v;  // exclusive
}

__global__ void k_scan_write(const int* __restrict__ cnt, const int* __restrict__ partial,
                             int* __restrict__ row_start, int* __restrict__ cursor, int N) {
    __shared__ int s[SCAN_CHUNK];
    int t = threadIdx.x;
    int i = blockIdx.x * SCAN_CHUNK + t;
    int v = (i < N) ? cnt[i] : 0;
    s[t] = v;
    __syncthreads();
    for (int off = 1; off < SCAN_CHUNK; off <<= 1) {
        int x = (t >= off) ? s[t - off] : 0;
        __syncthreads();
        s[t] += x;
        __syncthreads();
    }
    if (i < N) {
        int excl = s[t] - v + partial[blockIdx.x];
        row_start[i] = excl;
        cursor[i] = excl;
        if (i == N - 1) row_start[N] = excl + v;
    }
}

__global__ void k_fill(const int* __restrict__ ei, const float* __restrict__ ea,
                       const float* __restrict__ dinv, int* __restrict__ cursor,
                       int2* __restrict__ meta, int E) {
    int stride = gridDim.x * blockDim.x;
    for (int e = blockIdx.x * blockDim.x + threadIdx.x; e < E; e += stride) {
        int s = ei[e];
        int d = ei[E + e];
        float w = dinv[s] * ea[e] * dinv[d];
        int slot = atomicAdd(&cursor[d], 1);
        int2 m;
        m.x = s;
        m.y = __float_as_int(w);
        meta[slot] = m;
    }
}

__global__ void k_out_init(const float4* __restrict__ emb, float4* __restrict__ out, int n4) {
    int stride = gridDim.x * blockDim.x;
    for (int i = blockIdx.x * blockDim.x + threadIdx.x; i < n4; i += stride) {
        float4 v = emb[i];
        out[i] = make_float4(0.25f * v.x, 0.25f * v.y, 0.25f * v.z, 0.25f * v.w);
    }
}

// one wave (64 lanes) per destination node; lane d owns dim d.
template <bool WRITE_X>
__global__ void __launch_bounds__(256) k_layer(const float* __restrict__ xin,
                                               const int2* __restrict__ meta,
                                               const int* __restrict__ row_start,
                                               float* __restrict__ xout,
                                               float* __restrict__ out, int N) {
    int node = blockIdx.x * 4 + (threadIdx.x >> 6);
    if (node >= N) return;
    int lane = threadIdx.x & 63;
    int b = row_start[node];
    int e = row_start[node + 1];
    float acc = 0.0f;
    for (int i = b; i < e; ++i) {
        int2 m = meta[i];  // 8B broadcast load: (src, w)
        acc = fmaf(xin[m.x * 64 + lane], __int_as_float(m.y), acc);
    }
    int o = node * 64 + lane;
    if (WRITE_X) xout[o] = acc;
    out[o] += 0.25f * acc;
}

static inline size_t align_up(size_t x, size_t a) { return (x + a - 1) & ~(a - 1); }

extern "C" void kernel_launch(void* const* d_in, const int* in_sizes, int n_in,
                              void* d_out, int out_size, void* d_ws, size_t ws_size,
                              hipStream_t stream) {
    const float* emb = (const float*)d_in[0];
    const float* ea  = (const float*)d_in[1];
    const int*   ei  = (const int*)d_in[2];
    float* out = (float*)d_out;

    const int D = 64;
    const int N = in_sizes[0] / D;
    const int E = in_sizes[1];

    // workspace carve (all 256B-aligned)
    char* ws = (char*)d_ws;
    size_t off = 0;
    float* deg = (float*)(ws + off);        off = align_up(off + (size_t)N * 4, 256);
    int* cnt = (int*)(ws + off);            off = align_up(off + (size_t)N * 4, 256);
    int* row_start = (int*)(ws + off);      off = align_up(off + (size_t)(N + 1) * 4, 256);
    int* cursor = (int*)(ws + off);         off = align_up(off + (size_t)N * 4, 256);
    int* partial = (int*)(ws + off);        off = align_up(off + 1024 * 4, 256);
    int2* meta = (int2*)(ws + off);         off = align_up(off + (size_t)E * 8, 256);
    float* x1 = (float*)(ws + off);         off = align_up(off + (size_t)N * D * 4, 256);
    float* x2 = (float*)(ws + off);         off = align_up(off + (size_t)N * D * 4, 256);
    (void)ws_size;

    // deg and cnt are adjacent in element space? Not guaranteed after align; zero both.
    hipMemsetAsync(deg, 0, (size_t)N * 4, stream);
    hipMemsetAsync(cnt, 0, (size_t)N * 4, stream);

    int eb = (E + 255) / 256;
    k_deg_count<<<eb, 256, 0, stream>>>(ei, ea, deg, cnt, E);
    k_dinv<<<(N + 255) / 256, 256, 0, stream>>>(deg, N);

    int nblk = (N + SCAN_CHUNK - 1) / SCAN_CHUNK;  // 196 for N=100000 (must be <=256)
    k_chunk_sums<<<nblk, SCAN_CHUNK, 0, stream>>>(cnt, partial, N);
    k_scan_partials<<<1, 256, 0, stream>>>(partial, nblk);
    k_scan_write<<<nblk, SCAN_CHUNK, 0, stream>>>(cnt, partial, row_start, cursor, N);

    k_fill<<<eb, 256, 0, stream>>>(ei, ea, deg, cursor, meta, E);

    k_out_init<<<2048, 256, 0, stream>>>((const float4*)emb, (float4*)out, N * D / 4);

    int lb = (N + 3) / 4;
    k_layer<true><<<lb, 256, 0, stream>>>(emb, meta, row_start, x1, out, N);
    k_layer<true><<<lb, 256, 0, stream>>>(x1, meta, row_start, x2, out, N);
    k_layer<false><<<lb, 256, 0, stream>>>(x2, meta, row_start, nullptr, out, N);
}

// Round 2
// 349.389 us; speedup vs baseline: 1.6304x; 1.6304x over previous
//
#include <hip/hip_runtime.h>

// LightGCN propagation, CSR-by-destination formulation.
// N=100000 nodes, D=64 dims, E=1250000 edges (sizes read from in_sizes).
//
// R2 changes vs R1:
//  - k_layer: 16 lanes/node, float4 per lane (4 nodes/wave), edge loop
//    hand-unrolled x4 so 4 meta loads + 4 gathers are in flight per group
//    (R1 had MLP=1 -> 1376 cyc/edge, pure latency-bound at 21% HBM).
//  - out_init fused into layer 1 (out = alpha*(emb + acc)).

#define SCAN_CHUNK 512

__global__ void k_deg_count(const int* __restrict__ ei, const float* __restrict__ ea,
                            float* __restrict__ deg, int* __restrict__ cnt, int E) {
    int stride = gridDim.x * blockDim.x;
    for (int e = blockIdx.x * blockDim.x + threadIdx.x; e < E; e += stride) {
        int d = ei[E + e];
        atomicAdd(&deg[d], ea[e]);
        atomicAdd(&cnt[d], 1);
    }
}

__global__ void k_dinv(float* __restrict__ deg, int N) {
    int i = blockIdx.x * blockDim.x + threadIdx.x;
    if (i < N) {
        float v = deg[i];
        deg[i] = (v > 0.0f) ? rsqrtf(v) : 0.0f;
    }
}

__global__ void k_chunk_sums(const int* __restrict__ cnt, int* __restrict__ partial, int N) {
    __shared__ int s[SCAN_CHUNK];
    int t = threadIdx.x;
    int i = blockIdx.x * SCAN_CHUNK + t;
    s[t] = (i < N) ? cnt[i] : 0;
    __syncthreads();
    for (int off = SCAN_CHUNK / 2; off > 0; off >>= 1) {
        if (t < off) s[t] += s[t + off];
        __syncthreads();
    }
    if (t == 0) partial[blockIdx.x] = s[0];
}

// single block, exclusive-scans up to 256 partials in place (nblk=196 for N=100000)
__global__ void k_scan_partials(int* __restrict__ partial, int nblk) {
    __shared__ int s[256];
    int t = threadIdx.x;
    int v = (t < nblk) ? partial[t] : 0;
    s[t] = v;
    __syncthreads();
    for (int off = 1; off < 256; off <<= 1) {
        int x = (t >= off) ? s[t - off] : 0;
        __syncthreads();
        s[t] += x;
        __syncthreads();
    }
    if (t < nblk) partial[t] = s[t] - v;  // exclusive
}

__global__ void k_scan_write(const int* __restrict__ cnt, const int* __restrict__ partial,
                             int* __restrict__ row_start, int* __restrict__ cursor, int N) {
    __shared__ int s[SCAN_CHUNK];
    int t = threadIdx.x;
    int i = blockIdx.x * SCAN_CHUNK + t;
    int v = (i < N) ? cnt[i] : 0;
    s[t] = v;
    __syncthreads();
    for (int off = 1; off < SCAN_CHUNK; off <<= 1) {
        int x = (t >= off) ? s[t - off] : 0;
        __syncthreads();
        s[t] += x;
        __syncthreads();
    }
    if (i < N) {
        int excl = s[t] - v + partial[blockIdx.x];
        row_start[i] = excl;
        cursor[i] = excl;
        if (i == N - 1) row_start[N] = excl + v;
    }
}

__global__ void k_fill(const int* __restrict__ ei, const float* __restrict__ ea,
                       const float* __restrict__ dinv, int* __restrict__ cursor,
                       int2* __restrict__ meta, int E) {
    int stride = gridDim.x * blockDim.x;
    for (int e = blockIdx.x * blockDim.x + threadIdx.x; e < E; e += stride) {
        int s = ei[e];
        int d = ei[E + e];
        float w = dinv[s] * ea[e] * dinv[d];
        int slot = atomicAdd(&cursor[d], 1);
        int2 m;
        m.x = s;
        m.y = __float_as_int(w);
        meta[slot] = m;
    }
}

// 16-lane group per destination node; lane l owns dims 4l..4l+3 (float4).
// 4 nodes per wave. Edge loop unrolled x4 for memory-level parallelism.
// MODE: 0 = first layer  (out = alpha*(emb_row + acc), write x)
//       1 = middle layer (out += alpha*acc, write x)
//       2 = last layer   (out += alpha*acc, no x write)
template <int MODE>
__global__ void __launch_bounds__(256) k_layer(const float4* __restrict__ xin,
                                               const int2* __restrict__ meta,
                                               const int* __restrict__ row_start,
                                               float4* __restrict__ xout,
                                               float4* __restrict__ out, int N) {
    int g = (blockIdx.x * 256 + threadIdx.x) >> 4;  // group id = node
    if (g >= N) return;
    int l = threadIdx.x & 15;  // lane-in-group
    int b = row_start[g];
    int e = row_start[g + 1];

    float4 acc = make_float4(0.f, 0.f, 0.f, 0.f);
    int i = b;
    for (; i + 4 <= e; i += 4) {
        int2 m0 = meta[i];
        int2 m1 = meta[i + 1];
        int2 m2 = meta[i + 2];
        int2 m3 = meta[i + 3];
        float4 v0 = xin[m0.x * 16 + l];
        float4 v1 = xin[m1.x * 16 + l];
        float4 v2 = xin[m2.x * 16 + l];
        float4 v3 = xin[m3.x * 16 + l];
        float w0 = __int_as_float(m0.y);
        float w1 = __int_as_float(m1.y);
        float w2 = __int_as_float(m2.y);
        float w3 = __int_as_float(m3.y);
        acc.x = fmaf(v0.x, w0, acc.x);
        acc.y = fmaf(v0.y, w0, acc.y);
        acc.z = fmaf(v0.z, w0, acc.z);
        acc.w = fmaf(v0.w, w0, acc.w);
        acc.x = fmaf(v1.x, w1, acc.x);
        acc.y = fmaf(v1.y, w1, acc.y);
        acc.z = fmaf(v1.z, w1, acc.z);
        acc.w = fmaf(v1.w, w1, acc.w);
        acc.x = fmaf(v2.x, w2, acc.x);
        acc.y = fmaf(v2.y, w2, acc.y);
        acc.z = fmaf(v2.z, w2, acc.z);
        acc.w = fmaf(v2.w, w2, acc.w);
        acc.x = fmaf(v3.x, w3, acc.x);
        acc.y = fmaf(v3.y, w3, acc.y);
        acc.z = fmaf(v3.z, w3, acc.z);
        acc.w = fmaf(v3.w, w3, acc.w);
    }
    for (; i < e; ++i) {
        int2 m = meta[i];
        float4 v = xin[m.x * 16 + l];
        float w = __int_as_float(m.y);
        acc.x = fmaf(v.x, w, acc.x);
        acc.y = fmaf(v.y, w, acc.y);
        acc.z = fmaf(v.z, w, acc.z);
        acc.w = fmaf(v.w, w, acc.w);
    }

    int o = g * 16 + l;
    if (MODE == 0) {
        // fuse out_init: out = alpha*(emb_row + acc); xin here IS emb
        float4 ev = xin[o];
        float4 r;
        r.x = 0.25f * (ev.x + acc.x);
        r.y = 0.25f * (ev.y + acc.y);
        r.z = 0.25f * (ev.z + acc.z);
        r.w = 0.25f * (ev.w + acc.w);
        out[o] = r;
        xout[o] = acc;
    } else {
        float4 po = out[o];
        po.x = fmaf(0.25f, acc.x, po.x);
        po.y = fmaf(0.25f, acc.y, po.y);
        po.z = fmaf(0.25f, acc.z, po.z);
        po.w = fmaf(0.25f, acc.w, po.w);
        out[o] = po;
        if (MODE == 1) xout[o] = acc;
    }
}

static inline size_t align_up(size_t x, size_t a) { return (x + a - 1) & ~(a - 1); }

extern "C" void kernel_launch(void* const* d_in, const int* in_sizes, int n_in,
                              void* d_out, int out_size, void* d_ws, size_t ws_size,
                              hipStream_t stream) {
    const float* emb = (const float*)d_in[0];
    const float* ea  = (const float*)d_in[1];
    const int*   ei  = (const int*)d_in[2];
    float* out = (float*)d_out;

    const int D = 64;
    const int N = in_sizes[0] / D;
    const int E = in_sizes[1];

    // workspace carve (all 256B-aligned)
    char* ws = (char*)d_ws;
    size_t off = 0;
    float* deg = (float*)(ws + off);        off = align_up(off + (size_t)N * 4, 256);
    int* cnt = (int*)(ws + off);            off = align_up(off + (size_t)N * 4, 256);
    int* row_start = (int*)(ws + off);      off = align_up(off + (size_t)(N + 1) * 4, 256);
    int* cursor = (int*)(ws + off);         off = align_up(off + (size_t)N * 4, 256);
    int* partial = (int*)(ws + off);        off = align_up(off + 1024 * 4, 256);
    int2* meta = (int2*)(ws + off);         off = align_up(off + (size_t)E * 8, 256);
    float* x1 = (float*)(ws + off);         off = align_up(off + (size_t)N * D * 4, 256);
    float* x2 = (float*)(ws + off);         off = align_up(off + (size_t)N * D * 4, 256);
    (void)ws_size;

    hipMemsetAsync(deg, 0, (size_t)N * 4, stream);
    hipMemsetAsync(cnt, 0, (size_t)N * 4, stream);

    int eb = (E + 255) / 256;
    k_deg_count<<<eb, 256, 0, stream>>>(ei, ea, deg, cnt, E);
    k_dinv<<<(N + 255) / 256, 256, 0, stream>>>(deg, N);

    int nblk = (N + SCAN_CHUNK - 1) / SCAN_CHUNK;  // 196 for N=100000 (must be <=256)
    k_chunk_sums<<<nblk, SCAN_CHUNK, 0, stream>>>(cnt, partial, N);
    k_scan_partials<<<1, 256, 0, stream>>>(partial, nblk);
    k_scan_write<<<nblk, SCAN_CHUNK, 0, stream>>>(cnt, partial, row_start, cursor, N);

    k_fill<<<eb, 256, 0, stream>>>(ei, ea, deg, cursor, meta, E);

    int lb = (N * 16 + 255) / 256;  // 16 lanes per node
    k_layer<0><<<lb, 256, 0, stream>>>((const float4*)emb, meta, row_start,
                                       (float4*)x1, (float4*)out, N);
    k_layer<1><<<lb, 256, 0, stream>>>((const float4*)x1, meta, row_start,
                                       (float4*)x2, (float4*)out, N);
    k_layer<2><<<lb, 256, 0, stream>>>((const float4*)x2, meta, row_start,
                                       nullptr, (float4*)out, N);
}

// Round 3
// 254.465 us; speedup vs baseline: 2.2387x; 1.3730x over previous
//
#include <hip/hip_runtime.h>

// LightGCN propagation, CSR-by-destination formulation.
// N=100000 nodes, D=64 dims, E=1250000 edges (sizes read from in_sizes).
//
// R3 changes vs R2:
//  - k_deg_count: ONE native u64 atomic per edge, packing
//    {count:20 bits | fixed-point sum(attr)*2^32 : 44 bits}. R2's fp32
//    atomicAdd was a CAS loop (111us, WRITE_SIZE 78MB for an 800KB array).
//    The atomic's return value yields the edge's slot-within-row -> stored
//    to slot[e] (coalesced), so...
//  - k_fill: no atomics at all; meta[row_start[d] + slot[e]] = (src, w).

#define SCAN_CHUNK 512
#define SUM_BITS 44
#define SUM_MASK ((1ull << SUM_BITS) - 1)

__global__ void k_deg_count(const int* __restrict__ ei, const float* __restrict__ ea,
                            unsigned long long* __restrict__ pk, int* __restrict__ slot,
                            int E) {
    int stride = gridDim.x * blockDim.x;
    for (int e = blockIdx.x * blockDim.x + threadIdx.x; e < E; e += stride) {
        int d = ei[E + e];
        unsigned long long q = (unsigned long long)((double)ea[e] * 4294967296.0);
        unsigned long long inc = (1ull << SUM_BITS) | q;
        unsigned long long old = atomicAdd(&pk[d], inc);
        slot[e] = (int)(old >> SUM_BITS);
    }
}

// unpack: dinv[i] = rsqrt(sum) (0 if sum<=0), cnt[i] = count
__global__ void k_dinv(const unsigned long long* __restrict__ pk,
                       float* __restrict__ dinv, int* __restrict__ cnt, int N) {
    int i = blockIdx.x * blockDim.x + threadIdx.x;
    if (i < N) {
        unsigned long long p = pk[i];
        cnt[i] = (int)(p >> SUM_BITS);
        double s = (double)(p & SUM_MASK) * (1.0 / 4294967296.0);
        dinv[i] = (s > 0.0) ? rsqrtf((float)s) : 0.0f;
    }
}

__global__ void k_chunk_sums(const int* __restrict__ cnt, int* __restrict__ partial, int N) {
    __shared__ int s[SCAN_CHUNK];
    int t = threadIdx.x;
    int i = blockIdx.x * SCAN_CHUNK + t;
    s[t] = (i < N) ? cnt[i] : 0;
    __syncthreads();
    for (int off = SCAN_CHUNK / 2; off > 0; off >>= 1) {
        if (t < off) s[t] += s[t + off];
        __syncthreads();
    }
    if (t == 0) partial[blockIdx.x] = s[0];
}

// single block, exclusive-scans up to 256 partials in place (nblk=196 for N=100000)
__global__ void k_scan_partials(int* __restrict__ partial, int nblk) {
    __shared__ int s[256];
    int t = threadIdx.x;
    int v = (t < nblk) ? partial[t] : 0;
    s[t] = v;
    __syncthreads();
    for (int off = 1; off < 256; off <<= 1) {
        int x = (t >= off) ? s[t - off] : 0;
        __syncthreads();
        s[t] += x;
        __syncthreads();
    }
    if (t < nblk) partial[t] = s[t] - v;  // exclusive
}

__global__ void k_scan_write(const int* __restrict__ cnt, const int* __restrict__ partial,
                             int* __restrict__ row_start, int N) {
    __shared__ int s[SCAN_CHUNK];
    int t = threadIdx.x;
    int i = blockIdx.x * SCAN_CHUNK + t;
    int v = (i < N) ? cnt[i] : 0;
    s[t] = v;
    __syncthreads();
    for (int off = 1; off < SCAN_CHUNK; off <<= 1) {
        int x = (t >= off) ? s[t - off] : 0;
        __syncthreads();
        s[t] += x;
        __syncthreads();
    }
    if (i < N) {
        int excl = s[t] - v + partial[blockIdx.x];
        row_start[i] = excl;
        if (i == N - 1) row_start[N] = excl + v;
    }
}

// no atomics: slot[e] (from k_deg_count) gives position within the dst row
__global__ void k_fill(const int* __restrict__ ei, const float* __restrict__ ea,
                       const float* __restrict__ dinv, const int* __restrict__ row_start,
                       const int* __restrict__ slot, int2* __restrict__ meta, int E) {
    int stride = gridDim.x * blockDim.x;
    for (int e = blockIdx.x * blockDim.x + threadIdx.x; e < E; e += stride) {
        int s = ei[e];
        int d = ei[E + e];
        float w = dinv[s] * ea[e] * dinv[d];
        int2 m;
        m.x = s;
        m.y = __float_as_int(w);
        meta[row_start[d] + slot[e]] = m;
    }
}

// 16-lane group per destination node; lane l owns dims 4l..4l+3 (float4).
// 4 nodes per wave. Edge loop unrolled x4 for memory-level parallelism.
// MODE: 0 = first layer  (out = alpha*(emb_row + acc), write x)
//       1 = middle layer (out += alpha*acc, write x)
//       2 = last layer   (out += alpha*acc, no x write)
template <int MODE>
__global__ void __launch_bounds__(256) k_layer(const float4* __restrict__ xin,
                                               const int2* __restrict__ meta,
                                               const int* __restrict__ row_start,
                                               float4* __restrict__ xout,
                                               float4* __restrict__ out, int N) {
    int g = (blockIdx.x * 256 + threadIdx.x) >> 4;  // group id = node
    if (g >= N) return;
    int l = threadIdx.x & 15;  // lane-in-group
    int b = row_start[g];
    int e = row_start[g + 1];

    float4 acc = make_float4(0.f, 0.f, 0.f, 0.f);
    int i = b;
    for (; i + 4 <= e; i += 4) {
        int2 m0 = meta[i];
        int2 m1 = meta[i + 1];
        int2 m2 = meta[i + 2];
        int2 m3 = meta[i + 3];
        float4 v0 = xin[m0.x * 16 + l];
        float4 v1 = xin[m1.x * 16 + l];
        float4 v2 = xin[m2.x * 16 + l];
        float4 v3 = xin[m3.x * 16 + l];
        float w0 = __int_as_float(m0.y);
        float w1 = __int_as_float(m1.y);
        float w2 = __int_as_float(m2.y);
        float w3 = __int_as_float(m3.y);
        acc.x = fmaf(v0.x, w0, acc.x);
        acc.y = fmaf(v0.y, w0, acc.y);
        acc.z = fmaf(v0.z, w0, acc.z);
        acc.w = fmaf(v0.w, w0, acc.w);
        acc.x = fmaf(v1.x, w1, acc.x);
        acc.y = fmaf(v1.y, w1, acc.y);
        acc.z = fmaf(v1.z, w1, acc.z);
        acc.w = fmaf(v1.w, w1, acc.w);
        acc.x = fmaf(v2.x, w2, acc.x);
        acc.y = fmaf(v2.y, w2, acc.y);
        acc.z = fmaf(v2.z, w2, acc.z);
        acc.w = fmaf(v2.w, w2, acc.w);
        acc.x = fmaf(v3.x, w3, acc.x);
        acc.y = fmaf(v3.y, w3, acc.y);
        acc.z = fmaf(v3.z, w3, acc.z);
        acc.w = fmaf(v3.w, w3, acc.w);
    }
    for (; i < e; ++i) {
        int2 m = meta[i];
        float4 v = xin[m.x * 16 + l];
        float w = __int_as_float(m.y);
        acc.x = fmaf(v.x, w, acc.x);
        acc.y = fmaf(v.y, w, acc.y);
        acc.z = fmaf(v.z, w, acc.z);
        acc.w = fmaf(v.w, w, acc.w);
    }

    int o = g * 16 + l;
    if (MODE == 0) {
        // fuse out_init: out = alpha*(emb_row + acc); xin here IS emb
        float4 ev = xin[o];
        float4 r;
        r.x = 0.25f * (ev.x + acc.x);
        r.y = 0.25f * (ev.y + acc.y);
        r.z = 0.25f * (ev.z + acc.z);
        r.w = 0.25f * (ev.w + acc.w);
        out[o] = r;
        xout[o] = acc;
    } else {
        float4 po = out[o];
        po.x = fmaf(0.25f, acc.x, po.x);
        po.y = fmaf(0.25f, acc.y, po.y);
        po.z = fmaf(0.25f, acc.z, po.z);
        po.w = fmaf(0.25f, acc.w, po.w);
        out[o] = po;
        if (MODE == 1) xout[o] = acc;
    }
}

static inline size_t align_up(size_t x, size_t a) { return (x + a - 1) & ~(a - 1); }

extern "C" void kernel_launch(void* const* d_in, const int* in_sizes, int n_in,
                              void* d_out, int out_size, void* d_ws, size_t ws_size,
                              hipStream_t stream) {
    const float* emb = (const float*)d_in[0];
    const float* ea  = (const float*)d_in[1];
    const int*   ei  = (const int*)d_in[2];
    float* out = (float*)d_out;

    const int D = 64;
    const int N = in_sizes[0] / D;
    const int E = in_sizes[1];

    // workspace carve (all 256B-aligned)
    char* ws = (char*)d_ws;
    size_t off = 0;
    unsigned long long* pk = (unsigned long long*)(ws + off);
                                            off = align_up(off + (size_t)N * 8, 256);
    float* dinv = (float*)(ws + off);       off = align_up(off + (size_t)N * 4, 256);
    int* cnt = (int*)(ws + off);            off = align_up(off + (size_t)N * 4, 256);
    int* row_start = (int*)(ws + off);      off = align_up(off + (size_t)(N + 1) * 4, 256);
    int* partial = (int*)(ws + off);        off = align_up(off + 1024 * 4, 256);
    int* slot = (int*)(ws + off);           off = align_up(off + (size_t)E * 4, 256);
    int2* meta = (int2*)(ws + off);         off = align_up(off + (size_t)E * 8, 256);
    float* x1 = (float*)(ws + off);         off = align_up(off + (size_t)N * D * 4, 256);
    float* x2 = (float*)(ws + off);         off = align_up(off + (size_t)N * D * 4, 256);
    (void)ws_size;

    hipMemsetAsync(pk, 0, (size_t)N * 8, stream);

    int eb = (E + 255) / 256;
    k_deg_count<<<eb, 256, 0, stream>>>(ei, ea, pk, slot, E);
    k_dinv<<<(N + 255) / 256, 256, 0, stream>>>(pk, dinv, cnt, N);

    int nblk = (N + SCAN_CHUNK - 1) / SCAN_CHUNK;  // 196 for N=100000 (must be <=256)
    k_chunk_sums<<<nblk, SCAN_CHUNK, 0, stream>>>(cnt, partial, N);
    k_scan_partials<<<1, 256, 0, stream>>>(partial, nblk);
    k_scan_write<<<nblk, SCAN_CHUNK, 0, stream>>>(cnt, partial, row_start, N);

    k_fill<<<eb, 256, 0, stream>>>(ei, ea, dinv, row_start, slot, meta, E);

    int lb = (N * 16 + 255) / 256;  // 16 lanes per node
    k_layer<0><<<lb, 256, 0, stream>>>((const float4*)emb, meta, row_start,
                                       (float4*)x1, (float4*)out, N);
    k_layer<1><<<lb, 256, 0, stream>>>((const float4*)x1, meta, row_start,
                                       (float4*)x2, (float4*)out, N);
    k_layer<2><<<lb, 256, 0, stream>>>((const float4*)x2, meta, row_start,
                                       nullptr, (float4*)out, N);
}